// Round 3
// baseline (81.875 us; speedup 1.0000x reference)
//
#include <hip/hip_runtime.h>

// EquivDeepSet: out[b][c][iy][ix], c = {density, f1, f2}
// Separable Gaussian: Gram[g,n] = exp2(s*dx^2)*exp2(s*dy^2), s = -log2e/(2 l^2).
// Block = 64(ix) x 32(iy) output tile, 256 threads, each thread a 4x2 register
// tile -> 6 ds_read_b128 serve 32 pair-steps (LDS pipe off the critical path;
// VALU floor 4 ops/pair ~= 6.8 us). Split-K x8 over context (512 blocks),
// combined + divided by a tiny second kernel.

#define NCTX 1024
#define NG   128
#define NB   8
#define CH   128           // ctx per chunk staged in LDS
#define LPAD 4             // stride 132 words: 2-way bank alias on reads (free, m136)
#define STRIDE (CH + LPAD)

__device__ __forceinline__ void ctx_step(float ex0, float ex1, float ex2, float ex3,
                                         float ey0, float ey1, float y1, float y2,
                                         float (&d)[8], float (&a)[8], float (&c)[8])
{
    const float exv[4] = {ex0, ex1, ex2, ex3};
    const float eyv[2] = {ey0, ey1};
    #pragma unroll
    for (int i = 0; i < 4; ++i) {
        #pragma unroll
        for (int j = 0; j < 2; ++j) {
            const float w = exv[i] * eyv[j];         // Gram value
            d[i * 2 + j] += w;
            a[i * 2 + j] = fmaf(w, y1, a[i * 2 + j]);
            c[i * 2 + j] = fmaf(w, y2, c[i * 2 + j]);
        }
    }
}

template<int NSPLIT>
__global__ __launch_bounds__(256, 3)
void eds_partial(const float* __restrict__ Xc,    // [B][NCTX][2]
                 const float* __restrict__ Yc,    // [B][NCTX][2]
                 const float* __restrict__ gridp, // [NG*NG][2]
                 const float* __restrict__ logl,  // [1]
                 float* __restrict__ part)        // [NSPLIT][NB][3][NG*NG]
{
    constexpr int SC = NCTX / NSPLIT;   // ctx per block
    __shared__ float sEx[64][STRIDE];
    __shared__ float sEy[32][STRIDE];

    const int tid = threadIdx.x;
    const int ixl = tid & 15;
    const int iyl = tid >> 4;
    int blk = blockIdx.x;
    const int s = blk % NSPLIT; blk /= NSPLIT;
    const int tile = blk & 7;           // 2 x-tiles * 4 y-tiles of 64x32
    const int b    = blk >> 3;
    const int tx0 = (tile & 1) * 64;
    const int ty0 = (tile >> 1) * 32;

    const float ls = fminf(5.0f, fmaxf(-5.0f, logl[0]));
    const float l  = expf(ls);
    const float scale = -0.7213475204444817f / (l * l);   // -log2e/2 / l^2

    // grid[iy*NG+ix] = (xs[ix], ys[iy])
    float gx[4], gy[2];
    #pragma unroll
    for (int i = 0; i < 4; ++i) gx[i] = gridp[2 * (tx0 + ixl + 16 * i)];
    gy[0] = gridp[2 * ((ty0 + iyl) * NG) + 1];
    gy[1] = gridp[2 * ((ty0 + iyl + 16) * NG) + 1];

    float d[8], a[8], c[8];
    #pragma unroll
    for (int i = 0; i < 8; ++i) { d[i] = 0.0f; a[i] = 0.0f; c[i] = 0.0f; }

    for (int ch = 0; ch < SC / CH; ++ch) {
        const int cb = s * SC + ch * CH;
        __syncthreads();   // prior chunk's readers done before overwrite

        // ---- build Ex rows {ixl+16i}, cols [8*iyl, 8*iyl+8) ----
        {
            const float* Xp = Xc + ((size_t)b * NCTX + cb + 8 * iyl) * 2;
            float xv[8];
            #pragma unroll
            for (int t = 0; t < 4; ++t) {          // 8 ctx points (x coords)
                const float4 p = ((const float4*)Xp)[t];
                xv[2 * t]     = p.x;
                xv[2 * t + 1] = p.z;
            }
            #pragma unroll
            for (int i = 0; i < 4; ++i) {
                float4 e0, e1; float dx;
                dx = gx[i] - xv[0]; e0.x = exp2f(dx * dx * scale);
                dx = gx[i] - xv[1]; e0.y = exp2f(dx * dx * scale);
                dx = gx[i] - xv[2]; e0.z = exp2f(dx * dx * scale);
                dx = gx[i] - xv[3]; e0.w = exp2f(dx * dx * scale);
                dx = gx[i] - xv[4]; e1.x = exp2f(dx * dx * scale);
                dx = gx[i] - xv[5]; e1.y = exp2f(dx * dx * scale);
                dx = gx[i] - xv[6]; e1.z = exp2f(dx * dx * scale);
                dx = gx[i] - xv[7]; e1.w = exp2f(dx * dx * scale);
                *(float4*)&sEx[ixl + 16 * i][8 * iyl]     = e0;
                *(float4*)&sEx[ixl + 16 * i][8 * iyl + 4] = e1;
            }
        }
        // ---- build Ey rows {iyl, iyl+16}, cols [8*ixl, 8*ixl+8) ----
        {
            const float* Xq = Xc + ((size_t)b * NCTX + cb + 8 * ixl) * 2;
            float yv[8];
            #pragma unroll
            for (int t = 0; t < 4; ++t) {          // 8 ctx points (y coords)
                const float4 p = ((const float4*)Xq)[t];
                yv[2 * t]     = p.y;
                yv[2 * t + 1] = p.w;
            }
            #pragma unroll
            for (int j = 0; j < 2; ++j) {
                float4 e0, e1; float dy;
                dy = gy[j] - yv[0]; e0.x = exp2f(dy * dy * scale);
                dy = gy[j] - yv[1]; e0.y = exp2f(dy * dy * scale);
                dy = gy[j] - yv[2]; e0.z = exp2f(dy * dy * scale);
                dy = gy[j] - yv[3]; e0.w = exp2f(dy * dy * scale);
                dy = gy[j] - yv[4]; e1.x = exp2f(dy * dy * scale);
                dy = gy[j] - yv[5]; e1.y = exp2f(dy * dy * scale);
                dy = gy[j] - yv[6]; e1.z = exp2f(dy * dy * scale);
                dy = gy[j] - yv[7]; e1.w = exp2f(dy * dy * scale);
                *(float4*)&sEy[iyl + 16 * j][8 * ixl]     = e0;
                *(float4*)&sEy[iyl + 16 * j][8 * ixl + 4] = e1;
            }
        }
        __syncthreads();

        // block-uniform addresses -> scalar (s_load) path, off LDS/VMEM pipes
        const float4* yp = (const float4*)(Yc + ((size_t)b * NCTX + cb) * 2);

        #pragma unroll 4
        for (int k = 0; k < CH / 4; ++k) {
            const float4 ex0 = *(const float4*)&sEx[ixl     ][4 * k];
            const float4 ex1 = *(const float4*)&sEx[ixl + 16][4 * k];
            const float4 ex2 = *(const float4*)&sEx[ixl + 32][4 * k];
            const float4 ex3 = *(const float4*)&sEx[ixl + 48][4 * k];
            const float4 ey0 = *(const float4*)&sEy[iyl     ][4 * k];
            const float4 ey1 = *(const float4*)&sEy[iyl + 16][4 * k];
            const float4 ya = yp[2 * k];       // y[4k],y[4k+1]
            const float4 yb = yp[2 * k + 1];   // y[4k+2],y[4k+3]
            ctx_step(ex0.x, ex1.x, ex2.x, ex3.x, ey0.x, ey1.x, ya.x, ya.y, d, a, c);
            ctx_step(ex0.y, ex1.y, ex2.y, ex3.y, ey0.y, ey1.y, ya.z, ya.w, d, a, c);
            ctx_step(ex0.z, ex1.z, ex2.z, ex3.z, ey0.z, ey1.z, yb.x, yb.y, d, a, c);
            ctx_step(ex0.w, ex1.w, ex2.w, ex3.w, ey0.w, ey1.w, yb.z, yb.w, d, a, c);
        }
    }

    const size_t G = (size_t)NG * NG;
    float* P = part + ((size_t)(s * NB + b) * 3) * G;
    #pragma unroll
    for (int i = 0; i < 4; ++i) {
        #pragma unroll
        for (int j = 0; j < 2; ++j) {
            const int o = (ty0 + iyl + 16 * j) * NG + (tx0 + ixl + 16 * i);
            P[        o] = d[i * 2 + j];
            P[G     + o] = a[i * 2 + j];
            P[2 * G + o] = c[i * 2 + j];
        }
    }
}

template<int NSPLIT>
__global__ __launch_bounds__(256)
void eds_combine(const float* __restrict__ part, float* __restrict__ out)
{
    const size_t G = (size_t)NG * NG;
    const int t = blockIdx.x * 256 + threadIdx.x;  // NB*G threads
    const int b = t >> 14;           // / 16384
    const int o = t & (NG * NG - 1);
    float d = 0.0f, a1 = 0.0f, a2 = 0.0f;
    #pragma unroll
    for (int s = 0; s < NSPLIT; ++s) {
        const float* P = part + ((size_t)(s * NB + b) * 3) * G;
        d  += P[o];
        a1 += P[G + o];
        a2 += P[2 * G + o];
    }
    out[((size_t)b * 3 + 0) * G + o] = d;
    out[((size_t)b * 3 + 1) * G + o] = a1 / d;   // IEEE div, matches jnp
    out[((size_t)b * 3 + 2) * G + o] = a2 / d;
}

extern "C" void kernel_launch(void* const* d_in, const int* in_sizes, int n_in,
                              void* d_out, int out_size, void* d_ws, size_t ws_size,
                              hipStream_t stream) {
    const float* Xc = (const float*)d_in[0];
    const float* Yc = (const float*)d_in[1];
    const float* gr = (const float*)d_in[2];
    const float* ll = (const float*)d_in[3];
    float* out  = (float*)d_out;
    float* part = (float*)d_ws;

    const size_t need8 = (size_t)8 * NB * 3 * NG * NG * sizeof(float);  // 12.6 MB
    if (ws_size >= need8) {
        eds_partial<8><<<dim3(NB * 8 * 8), dim3(256), 0, stream>>>(Xc, Yc, gr, ll, part);
        eds_combine<8><<<dim3(NB * NG * NG / 256), dim3(256), 0, stream>>>(part, out);
    } else {
        eds_partial<1><<<dim3(NB * 8), dim3(256), 0, stream>>>(Xc, Yc, gr, ll, part);
        eds_combine<1><<<dim3(NB * NG * NG / 256), dim3(256), 0, stream>>>(part, out);
    }
}